// Round 6
// baseline (12592.642 us; speedup 1.0000x reference)
//
#include <hip/hip_runtime.h>
#include <stdint.h>

typedef unsigned long long u64;
typedef __attribute__((ext_vector_type(8))) short short8;   // 8 bf16
typedef __attribute__((ext_vector_type(4))) float f32x4;

// Problem constants
#define NROWS 16384   // B*H*W
#define CDIM  256
#define NEMB  8192

// d_out layout (float offsets): z | z_q | indices | one_hot
#define Z_OFF   0ull
#define ZQ_OFF  4194304ull
#define IDX_OFF 8388608ull
#define OH_OFF  8404992ull

// ws layout: es[8192] @0, zs[16384] @32KB, keys (8MB) @128KB. Total 8.5MB (R3-proven).
#define ES_OFF_BYTES   0
#define ZS_OFF_BYTES   32768
#define KEYS_OFF_BYTES 131072
// E bf16 halves (8MB) in the LAST 256 one-hot rows; Z halves (16MB) in z_q region.
#define EHL_ROW0 16128

#define THR_ULP 4u    // flag margin (honest |d~-d| < 1 grid ulp)
#define TRIP_ULP 8u   // self-heal trip threshold (honest |mB-mT| <= ~2)

// order-preserving f32 -> u32 map (monotone increasing)
__device__ __forceinline__ unsigned fmap(float x) {
    unsigned u = __float_as_uint(x);
    return (u & 0x80000000u) ? ~u : (u | 0x80000000u);
}

// ---------------------------------------------------------------------------
// Kernel A: transpose z_e [B,C,H,W] -> z [B,H,W,C]  (unchanged, proven)
// ---------------------------------------------------------------------------
__global__ __launch_bounds__(256) void k_transpose(const float* __restrict__ ze,
                                                   float* __restrict__ z) {
    __shared__ float T[64][65];
    int b = blockIdx.z, ct = blockIdx.x, ht = blockIdx.y;
    int c0 = ct * 64, hw0 = ht * 64;
    int lane = threadIdx.x & 63, grp = threadIdx.x >> 6;
    #pragma unroll
    for (int i = 0; i < 16; ++i) {
        int cl = grp + i * 4;
        T[cl][lane] = ze[((size_t)(b * 256 + c0 + cl)) * 1024 + hw0 + lane];
    }
    __syncthreads();
    #pragma unroll
    for (int i = 0; i < 16; ++i) {
        int hwl = grp + i * 4;
        z[((size_t)(b * 1024 + hw0 + hwl)) * 256 + c0 + lane] = T[lane][hwl];
    }
}

// ---------------------------------------------------------------------------
// numpy pairwise_sum emulation (unchanged, proven bit-exact)
// ---------------------------------------------------------------------------
__device__ __forceinline__ float pw128sq(const float* __restrict__ x) {
    float r[8];
    #pragma unroll
    for (int j = 0; j < 8; ++j) r[j] = __fmul_rn(x[j], x[j]);
    #pragma unroll
    for (int i = 8; i < 128; i += 8) {
        #pragma unroll
        for (int j = 0; j < 8; ++j)
            r[j] = __fadd_rn(r[j], __fmul_rn(x[i + j], x[i + j]));
    }
    return __fadd_rn(__fadd_rn(__fadd_rn(r[0], r[1]), __fadd_rn(r[2], r[3])),
                     __fadd_rn(__fadd_rn(r[4], r[5]), __fadd_rn(r[6], r[7])));
}

__global__ __launch_bounds__(256) void k_rowsq(const float* __restrict__ X,
                                               float* __restrict__ out,
                                               int nrows) {
    int r = blockIdx.x * 256 + threadIdx.x;
    if (r >= nrows) return;
    const float* x = &X[(size_t)r * 256];
    out[r] = __fadd_rn(pw128sq(x), pw128sq(x + 128));
}

__global__ __launch_bounds__(256) void k_zsq(const float* __restrict__ ze,
                                             float* __restrict__ zs) {
    int t = blockIdx.x * 256 + threadIdx.x;
    int b = t >> 10, hw = t & 1023;
    const float* base = ze + ((size_t)b * 256) * 1024 + hw;
    float half[2];
    #pragma unroll
    for (int hB = 0; hB < 2; ++hB) {
        const float* p = base + (size_t)(hB * 128) * 1024;
        float r[8];
        #pragma unroll
        for (int j = 0; j < 8; ++j) {
            float v = p[(size_t)j * 1024];
            r[j] = __fmul_rn(v, v);
        }
        #pragma unroll
        for (int i = 8; i < 128; i += 8) {
            #pragma unroll
            for (int j = 0; j < 8; ++j) {
                float v = p[(size_t)(i + j) * 1024];
                r[j] = __fadd_rn(r[j], __fmul_rn(v, v));
            }
        }
        half[hB] = __fadd_rn(__fadd_rn(__fadd_rn(r[0], r[1]), __fadd_rn(r[2], r[3])),
                             __fadd_rn(__fadd_rn(r[4], r[5]), __fadd_rn(r[6], r[7])));
    }
    zs[t] = __fadd_rn(half[0], half[1]);
}

// ---------------------------------------------------------------------------
// Kernel S: split X into bf16 (hi,lo) pairs, pre-tiled
// [rowblock][kchunk(8)][hl(2)][p(4)][row128][16B].  (unchanged from R5)
// ---------------------------------------------------------------------------
__global__ __launch_bounds__(256) void k_split(const float* __restrict__ X,
                                               char* __restrict__ HL,
                                               int nrows) {
    int t = blockIdx.x * 256 + threadIdx.x;
    if (t >= nrows * 32) return;
    int row = t >> 5, c8 = t & 31;
    const float* src = X + (size_t)row * 256 + c8 * 8;
    float4 f0 = *(const float4*)src;
    float4 f1 = *(const float4*)(src + 4);
    float f[8] = {f0.x, f0.y, f0.z, f0.w, f1.x, f1.y, f1.z, f1.w};
    unsigned hb[8], lb[8];
    #pragma unroll
    for (int j = 0; j < 8; ++j) {
        unsigned b = __float_as_uint(f[j]);
        hb[j] = b;
        float hi = __uint_as_float(b & 0xffff0000u);
        lb[j] = __float_as_uint(f[j] - hi);
    }
    uint4 hh, ll;
    hh.x = (hb[0] >> 16) | (hb[1] & 0xffff0000u);
    hh.y = (hb[2] >> 16) | (hb[3] & 0xffff0000u);
    hh.z = (hb[4] >> 16) | (hb[5] & 0xffff0000u);
    hh.w = (hb[6] >> 16) | (hb[7] & 0xffff0000u);
    ll.x = (lb[0] >> 16) | (lb[1] & 0xffff0000u);
    ll.y = (lb[2] >> 16) | (lb[3] & 0xffff0000u);
    ll.z = (lb[4] >> 16) | (lb[5] & 0xffff0000u);
    ll.w = (lb[6] >> 16) | (lb[7] & 0xffff0000u);
    int rb = row >> 7, rloc = row & 127, kc = c8 >> 2, p = c8 & 3;
    size_t base = ((size_t)(rb * 8 + kc)) * 16384 + (size_t)p * 2048 + (size_t)rloc * 16;
    *(uint4*)(HL + base) = hh;
    *(uint4*)(HL + base + 8192) = ll;
}

// ---------------------------------------------------------------------------
// Kernel C: split-bf16 MFMA GEMM. ONE delta vs R5: staging is now plain
// global loads + ds_write_b128 (identity copy) — no global_load_lds.
// ---------------------------------------------------------------------------
__global__ __launch_bounds__(256) void k_dist(const char* __restrict__ ZHL,
                                              const char* __restrict__ EHL,
                                              const float* __restrict__ es,
                                              const float* __restrict__ zs,
                                              float* __restrict__ oh,
                                              u64* __restrict__ keys) {
    __shared__ __align__(16) char smem[33792];   // staging 32KB ∪ red[128][33] u64
    u64* red = (u64*)smem;

    int bx = blockIdx.x;   // col block 0..63
    int by = blockIdx.y;   // row block 0..127
    int tid = threadIdx.x;
    int w = tid >> 6, lane = tid & 63;
    int p = lane >> 4, l15 = lane & 15;
    int rowhalf = (w & 1) * 64, colhalf = (w >> 1) * 64;
    int row0 = by * 128, col0 = bx * 128;

    f32x4 acc[4][4] = {};

    const char* asrc = ZHL + ((size_t)(by * 8)) * 16384;
    const char* bsrc = EHL + ((size_t)(bx * 8)) * 16384;

    for (int kc = 0; kc < 8; ++kc) {
        if (kc) __syncthreads();
        // identity copy of 32 KB: A kchunk -> smem[0,16K), B kchunk -> [16K,32K)
        const char* ak = asrc + (size_t)kc * 16384;
        const char* bk = bsrc + (size_t)kc * 16384;
        #pragma unroll
        for (int it = 0; it < 8; ++it) {
            int off = it * 4096 + tid * 16;
            uint4 v = (it < 4) ? *(const uint4*)(ak + off)
                               : *(const uint4*)(bk + off - 16384);
            *(uint4*)(smem + off) = v;
        }
        __syncthreads();

        short8 Ah[4], Al[4], Bh[4], Bl[4];
        #pragma unroll
        for (int rt = 0; rt < 4; ++rt) {
            int r = rowhalf + rt * 16 + l15;
            Ah[rt] = *(const short8*)(smem + p * 2048 + r * 16);
            Al[rt] = *(const short8*)(smem + 8192 + p * 2048 + r * 16);
        }
        #pragma unroll
        for (int ct = 0; ct < 4; ++ct) {
            int c = colhalf + ct * 16 + l15;
            Bh[ct] = *(const short8*)(smem + 16384 + p * 2048 + c * 16);
            Bl[ct] = *(const short8*)(smem + 24576 + p * 2048 + c * 16);
        }
        #pragma unroll
        for (int rt = 0; rt < 4; ++rt)
            #pragma unroll
            for (int ct = 0; ct < 4; ++ct) {
                acc[rt][ct] = __builtin_amdgcn_mfma_f32_16x16x32_bf16(
                    Al[rt], Bh[ct], acc[rt][ct], 0, 0, 0);
                acc[rt][ct] = __builtin_amdgcn_mfma_f32_16x16x32_bf16(
                    Ah[rt], Bl[ct], acc[rt][ct], 0, 0, 0);
                acc[rt][ct] = __builtin_amdgcn_mfma_f32_16x16x32_bf16(
                    Ah[rt], Bh[ct], acc[rt][ct], 0, 0, 0);
            }
    }
    __syncthreads();   // before smem reuse as red

    // epilogue: d~ = fl(fl(zs+es) - 2*dot~); per-row min over this block's cols.
    float esv[4], zsv[4][4];
    #pragma unroll
    for (int ct = 0; ct < 4; ++ct) esv[ct] = es[col0 + colhalf + ct * 16 + l15];
    #pragma unroll
    for (int rt = 0; rt < 4; ++rt)
        #pragma unroll
        for (int reg = 0; reg < 4; ++reg)
            zsv[rt][reg] = zs[row0 + rowhalf + rt * 16 + p * 4 + reg];

    #pragma unroll
    for (int rt = 0; rt < 4; ++rt) {
        #pragma unroll
        for (int reg = 0; reg < 4; ++reg) {
            u64 best = ~0ull;
            #pragma unroll
            for (int ct = 0; ct < 4; ++ct) {
                float t1 = __fadd_rn(zsv[rt][reg], esv[ct]);
                float d  = __fsub_rn(t1, __fmul_rn(2.0f, acc[rt][ct][reg]));
                unsigned c = (unsigned)(col0 + colhalf + ct * 16 + l15);
                u64 key = ((u64)fmap(d) << 32) | c;
                if (key < best) best = key;
            }
            int r = rowhalf + rt * 16 + p * 4 + reg;
            red[r * 33 + (w >> 1) * 16 + l15] = best;
        }
    }
    __syncthreads();
    if (tid < 128) {
        u64 best = ~0ull;
        #pragma unroll
        for (int s = 0; s < 32; ++s) {
            u64 k = red[tid * 33 + s];
            if (k < best) best = k;
        }
        keys[((size_t)(row0 + tid)) * 64 + bx] = best;
    }

    // fused one-hot zero fill — skip EHL-resident rows (zeroed by k_final)
    if (by < 126) {
        float4 z4 = make_float4(0.f, 0.f, 0.f, 0.f);
        #pragma unroll
        for (int it = 0; it < 16; ++it) {
            int f4 = tid + it * 256;
            int r = f4 >> 5, q = f4 & 31;
            *(float4*)&oh[((size_t)(row0 + r)) * NEMB + col0 + q * 4] = z4;
        }
    }
}

// ---------------------------------------------------------------------------
// exact np-f32 distance key (R3-proven chain)
// ---------------------------------------------------------------------------
__device__ __forceinline__ u64 exact_key(const float* zrow, const float* __restrict__ E,
                                         const float* __restrict__ es, float zsn, int k) {
    const float* e = &E[(size_t)k * 256];
    float dot = 0.0f;
    for (int c = 0; c < 256; ++c) dot = fmaf(zrow[c], e[c], dot);
    float t1 = __fadd_rn(zsn, es[k]);
    float d  = __fsub_rn(t1, __fmul_rn(2.0f, dot));
    return ((u64)fmap(d) << 32) | (unsigned)k;
}

// ---------------------------------------------------------------------------
// Kernel D: per-row finalize, SELF-HEALING. Flagged-chunk exact rescue; if the
// exact best disagrees with the d~ floor by >8 ulp (or nflag>16), full exact
// scan of all 64 chunks — np-exact even under arbitrary d~ corruption.
// ---------------------------------------------------------------------------
__global__ __launch_bounds__(256) void k_final(const float* __restrict__ Z,
                                               const float* __restrict__ E,
                                               const float* __restrict__ es,
                                               const float* __restrict__ zs,
                                               const u64* __restrict__ keys,
                                               float* __restrict__ zq,
                                               float* __restrict__ idxf,
                                               float* __restrict__ oh) {
    __shared__ u64 kch[64];
    __shared__ float zrow[256];
    __shared__ u64 rmin[256];
    __shared__ int flaglist[64];
    __shared__ int nflag;
    __shared__ u64 mtop;
    __shared__ int strip;

    int n = blockIdx.x;
    int tid = threadIdx.x;

    if (tid < 64) kch[tid] = keys[(size_t)n * 64 + tid];
    zrow[tid] = Z[(size_t)n * 256 + tid];
    __syncthreads();
    if (tid == 0) {
        u64 m = ~0ull;
        for (int s = 0; s < 64; ++s) if (kch[s] < m) m = kch[s];
        unsigned thr = (unsigned)(m >> 32) + THR_ULP;
        int nf = 0;
        for (int s = 0; s < 64; ++s)
            if ((unsigned)(kch[s] >> 32) <= thr) flaglist[nf++] = s;
        nflag = nf;
        mtop = m;
    }
    __syncthreads();

    float zsn = zs[n];
    u64 best = ~0ull;
    for (int f = 0; f < nflag; ++f)
        if (tid < 128) {
            u64 key = exact_key(zrow, E, es, zsn, flaglist[f] * 128 + tid);
            if (key < best) best = key;
        }
    rmin[tid] = best;
    __syncthreads();
    for (int s = 128; s > 0; s >>= 1) {
        if (tid < s) { if (rmin[tid + s] < rmin[tid]) rmin[tid] = rmin[tid + s]; }
        __syncthreads();
    }
    if (tid == 0) {
        unsigned mT = (unsigned)(mtop >> 32);
        unsigned mB = (unsigned)(rmin[0] >> 32);
        strip = (mB > mT + TRIP_ULP) || (mT > mB + TRIP_ULP) || (nflag > 16);
    }
    __syncthreads();

    if (strip) {   // self-heal: exact scan of ALL chunks (np-exact regardless of d~)
        best = ~0ull;
        for (int ch = 0; ch < 64; ++ch)
            if (tid < 128) {
                u64 key = exact_key(zrow, E, es, zsn, ch * 128 + tid);
                if (key < best) best = key;
            }
        rmin[tid] = best;
        __syncthreads();
        for (int s = 128; s > 0; s >>= 1) {
            if (tid < s) { if (rmin[tid + s] < rmin[tid]) rmin[tid] = rmin[tid + s]; }
            __syncthreads();
        }
    }
    int idx = (int)(rmin[0] & 0xffffffffu);

    // tail rows hosted EHL scratch during k_dist — zero them here
    if (n >= EHL_ROW0) {
        float* ohrow = oh + (size_t)n * NEMB;
        float4 z4 = make_float4(0.f, 0.f, 0.f, 0.f);
        #pragma unroll
        for (int it = 0; it < 8; ++it)
            *(float4*)&ohrow[(it * 256 + tid) * 4] = z4;
        __syncthreads();
    }

    zq[(size_t)n * 256 + tid] = E[(size_t)idx * 256 + tid];
    if (tid == 0) {
        idxf[n] = (float)idx;
        oh[(size_t)n * NEMB + idx] = 1.0f;
    }
}

// ---------------------------------------------------------------------------
extern "C" void kernel_launch(void* const* d_in, const int* in_sizes, int n_in,
                              void* d_out, int out_size, void* d_ws, size_t ws_size,
                              hipStream_t stream) {
    const float* ze  = (const float*)d_in[0];   // [16,256,32,32]
    const float* emb = (const float*)d_in[1];   // [8192,256]
    float* out = (float*)d_out;
    float* z    = out + Z_OFF;
    float* zq   = out + ZQ_OFF;
    float* idxf = out + IDX_OFF;
    float* oh   = out + OH_OFF;
    float* es   = (float*)((char*)d_ws + ES_OFF_BYTES);
    float* zs   = (float*)((char*)d_ws + ZS_OFF_BYTES);
    u64*   keys = (u64*)((char*)d_ws + KEYS_OFF_BYTES);
    char*  ZHL  = (char*)zq;                                   // 16 MB (z_q region)
    char*  EHL  = (char*)(oh + (size_t)EHL_ROW0 * NEMB);       // 8 MB (one-hot tail)

    k_transpose<<<dim3(4, 16, 16), 256, 0, stream>>>(ze, z);
    k_zsq<<<NROWS / 256, 256, 0, stream>>>(ze, zs);
    k_rowsq<<<NEMB / 256, 256, 0, stream>>>(emb, es, NEMB);
    k_split<<<NROWS * 32 / 256, 256, 0, stream>>>(z, ZHL, NROWS);
    k_split<<<NEMB * 32 / 256, 256, 0, stream>>>(emb, EHL, NEMB);
    k_dist<<<dim3(64, 128), 256, 0, stream>>>(ZHL, EHL, es, zs, oh, keys);
    k_final<<<NROWS, 256, 0, stream>>>(z, emb, es, zs, keys, zq, idxf, oh);
}

// Round 7
// 1196.960 us; speedup vs baseline: 10.5205x; 10.5205x over previous
//
#include <hip/hip_runtime.h>
#include <stdint.h>

typedef unsigned long long u64;
typedef unsigned u32;
typedef __attribute__((ext_vector_type(8))) short short8;   // 8 bf16
typedef __attribute__((ext_vector_type(4))) float f32x4;

// Problem constants
#define NROWS 16384   // B*H*W
#define CDIM  256
#define NEMB  8192

// d_out layout (float offsets): z | z_q | indices | one_hot
#define Z_OFF   0ull
#define ZQ_OFF  4194304ull
#define IDX_OFF 8388608ull
#define OH_OFF  8404992ull

// ws layout (total 8.25 MB, under the R3-proven 8.5 MB budget):
#define ES_OFF_BYTES     0        // es[8192] f32 (32 KB)
#define ZS_OFF_BYTES     32768    // zs[16384] f32 (64 KB)
#define ORIENT_OFF_BYTES 98304    // int
#define KEYSA_OFF_BYTES  131072   // u32[16384*64] (4 MB)
#define KEYSB_OFF_BYTES  4325376  // u32[16384*64] (4 MB)
// E bf16 halves (8MB) in the LAST 256 one-hot rows (zeroed by k_final);
// Z bf16 halves (16MB) in the z_q output region (rewritten by k_final).
#define EHL_ROW0 16128

#define THR_ULP 4u    // flag margin (honest |d~-d| < 1 grid ulp)
#define TRIP_ULP 8u   // per-row self-heal trip

// order-preserving f32 -> u32 map (monotone increasing)
__device__ __forceinline__ u32 fmap(float x) {
    u32 u = __float_as_uint(x);
    return (u & 0x80000000u) ? ~u : (u | 0x80000000u);
}
__device__ __forceinline__ u32 udiff(u32 a, u32 b) { return a > b ? a - b : b - a; }

// ---------------------------------------------------------------------------
// Kernel A: transpose z_e [B,C,H,W] -> z [B,H,W,C]  (proven)
// ---------------------------------------------------------------------------
__global__ __launch_bounds__(256) void k_transpose(const float* __restrict__ ze,
                                                   float* __restrict__ z) {
    __shared__ float T[64][65];
    int b = blockIdx.z, ct = blockIdx.x, ht = blockIdx.y;
    int c0 = ct * 64, hw0 = ht * 64;
    int lane = threadIdx.x & 63, grp = threadIdx.x >> 6;
    #pragma unroll
    for (int i = 0; i < 16; ++i) {
        int cl = grp + i * 4;
        T[cl][lane] = ze[((size_t)(b * 256 + c0 + cl)) * 1024 + hw0 + lane];
    }
    __syncthreads();
    #pragma unroll
    for (int i = 0; i < 16; ++i) {
        int hwl = grp + i * 4;
        z[((size_t)(b * 1024 + hw0 + hwl)) * 256 + c0 + lane] = T[lane][hwl];
    }
}

// ---------------------------------------------------------------------------
// numpy pairwise_sum emulation (proven bit-exact)
// ---------------------------------------------------------------------------
__device__ __forceinline__ float pw128sq(const float* __restrict__ x) {
    float r[8];
    #pragma unroll
    for (int j = 0; j < 8; ++j) r[j] = __fmul_rn(x[j], x[j]);
    #pragma unroll
    for (int i = 8; i < 128; i += 8) {
        #pragma unroll
        for (int j = 0; j < 8; ++j)
            r[j] = __fadd_rn(r[j], __fmul_rn(x[i + j], x[i + j]));
    }
    return __fadd_rn(__fadd_rn(__fadd_rn(r[0], r[1]), __fadd_rn(r[2], r[3])),
                     __fadd_rn(__fadd_rn(r[4], r[5]), __fadd_rn(r[6], r[7])));
}

__global__ __launch_bounds__(256) void k_rowsq(const float* __restrict__ X,
                                               float* __restrict__ out,
                                               int nrows) {
    int r = blockIdx.x * 256 + threadIdx.x;
    if (r >= nrows) return;
    const float* x = &X[(size_t)r * 256];
    out[r] = __fadd_rn(pw128sq(x), pw128sq(x + 128));
}

__global__ __launch_bounds__(256) void k_zsq(const float* __restrict__ ze,
                                             float* __restrict__ zs) {
    int t = blockIdx.x * 256 + threadIdx.x;
    int b = t >> 10, hw = t & 1023;
    const float* base = ze + ((size_t)b * 256) * 1024 + hw;
    float half[2];
    #pragma unroll
    for (int hB = 0; hB < 2; ++hB) {
        const float* p = base + (size_t)(hB * 128) * 1024;
        float r[8];
        #pragma unroll
        for (int j = 0; j < 8; ++j) {
            float v = p[(size_t)j * 1024];
            r[j] = __fmul_rn(v, v);
        }
        #pragma unroll
        for (int i = 8; i < 128; i += 8) {
            #pragma unroll
            for (int j = 0; j < 8; ++j) {
                float v = p[(size_t)(i + j) * 1024];
                r[j] = __fadd_rn(r[j], __fmul_rn(v, v));
            }
        }
        half[hB] = __fadd_rn(__fadd_rn(__fadd_rn(r[0], r[1]), __fadd_rn(r[2], r[3])),
                             __fadd_rn(__fadd_rn(r[4], r[5]), __fadd_rn(r[6], r[7])));
    }
    zs[t] = __fadd_rn(half[0], half[1]);
}

// ---------------------------------------------------------------------------
// Kernel S: split X into bf16 (hi,lo) pairs, pre-tiled
// [rowblock][kchunk(8)][hl(2)][p(4)][row128][16B].  (unchanged)
// ---------------------------------------------------------------------------
__global__ __launch_bounds__(256) void k_split(const float* __restrict__ X,
                                               char* __restrict__ HL,
                                               int nrows) {
    int t = blockIdx.x * 256 + threadIdx.x;
    if (t >= nrows * 32) return;
    int row = t >> 5, c8 = t & 31;
    const float* src = X + (size_t)row * 256 + c8 * 8;
    float4 f0 = *(const float4*)src;
    float4 f1 = *(const float4*)(src + 4);
    float f[8] = {f0.x, f0.y, f0.z, f0.w, f1.x, f1.y, f1.z, f1.w};
    unsigned hb[8], lb[8];
    #pragma unroll
    for (int j = 0; j < 8; ++j) {
        unsigned b = __float_as_uint(f[j]);
        hb[j] = b;
        float hi = __uint_as_float(b & 0xffff0000u);
        lb[j] = __float_as_uint(f[j] - hi);
    }
    uint4 hh, ll;
    hh.x = (hb[0] >> 16) | (hb[1] & 0xffff0000u);
    hh.y = (hb[2] >> 16) | (hb[3] & 0xffff0000u);
    hh.z = (hb[4] >> 16) | (hb[5] & 0xffff0000u);
    hh.w = (hb[6] >> 16) | (hb[7] & 0xffff0000u);
    ll.x = (lb[0] >> 16) | (lb[1] & 0xffff0000u);
    ll.y = (lb[2] >> 16) | (lb[3] & 0xffff0000u);
    ll.z = (lb[4] >> 16) | (lb[5] & 0xffff0000u);
    ll.w = (lb[6] >> 16) | (lb[7] & 0xffff0000u);
    int rb = row >> 7, rloc = row & 127, kc = c8 >> 2, p = c8 & 3;
    size_t base = ((size_t)(rb * 8 + kc)) * 16384 + (size_t)p * 2048 + (size_t)rloc * 16;
    *(uint4*)(HL + base) = hh;
    *(uint4*)(HL + base + 8192) = ll;
}

// ---------------------------------------------------------------------------
// Kernel C: split-bf16 MFMA GEMM (R6 staging, proven-benign). Epilogue emits
// per-(row, chunk) min d~ VALUES (u32) under BOTH D-layout hypotheses:
//   hypA: acc[rt][ct][reg] = dot(row rt*16+p*4+reg, col ct*16+l15)
//   hypB: acc[rt][ct][reg] = dot(row rt*16+l15,    col ct*16+p*4+reg)
// ---------------------------------------------------------------------------
__global__ __launch_bounds__(256) void k_dist(const char* __restrict__ ZHL,
                                              const char* __restrict__ EHL,
                                              const float* __restrict__ es,
                                              const float* __restrict__ zs,
                                              float* __restrict__ oh,
                                              u32* __restrict__ keysA,
                                              u32* __restrict__ keysB) {
    __shared__ __align__(16) char smem[33792];   // staging 32KB ∪ redA/redB
    int bx = blockIdx.x;   // col block 0..63
    int by = blockIdx.y;   // row block 0..127
    int tid = threadIdx.x;
    int w = tid >> 6, lane = tid & 63;
    int p = lane >> 4, l15 = lane & 15;
    int rowhalf = (w & 1) * 64, colhalf = (w >> 1) * 64;
    int row0 = by * 128, col0 = bx * 128;

    f32x4 acc[4][4] = {};

    const char* asrc = ZHL + ((size_t)(by * 8)) * 16384;
    const char* bsrc = EHL + ((size_t)(bx * 8)) * 16384;

    for (int kc = 0; kc < 8; ++kc) {
        if (kc) __syncthreads();
        const char* ak = asrc + (size_t)kc * 16384;
        const char* bk = bsrc + (size_t)kc * 16384;
        #pragma unroll
        for (int it = 0; it < 8; ++it) {
            int off = it * 4096 + tid * 16;
            uint4 v = (it < 4) ? *(const uint4*)(ak + off)
                               : *(const uint4*)(bk + off - 16384);
            *(uint4*)(smem + off) = v;
        }
        __syncthreads();

        short8 Ah[4], Al[4], Bh[4], Bl[4];
        #pragma unroll
        for (int rt = 0; rt < 4; ++rt) {
            int r = rowhalf + rt * 16 + l15;
            Ah[rt] = *(const short8*)(smem + p * 2048 + r * 16);
            Al[rt] = *(const short8*)(smem + 8192 + p * 2048 + r * 16);
        }
        #pragma unroll
        for (int ct = 0; ct < 4; ++ct) {
            int c = colhalf + ct * 16 + l15;
            Bh[ct] = *(const short8*)(smem + 16384 + p * 2048 + c * 16);
            Bl[ct] = *(const short8*)(smem + 24576 + p * 2048 + c * 16);
        }
        #pragma unroll
        for (int rt = 0; rt < 4; ++rt)
            #pragma unroll
            for (int ct = 0; ct < 4; ++ct) {
                acc[rt][ct] = __builtin_amdgcn_mfma_f32_16x16x32_bf16(
                    Al[rt], Bh[ct], acc[rt][ct], 0, 0, 0);
                acc[rt][ct] = __builtin_amdgcn_mfma_f32_16x16x32_bf16(
                    Ah[rt], Bl[ct], acc[rt][ct], 0, 0, 0);
                acc[rt][ct] = __builtin_amdgcn_mfma_f32_16x16x32_bf16(
                    Ah[rt], Bh[ct], acc[rt][ct], 0, 0, 0);
            }
    }
    __syncthreads();   // before smem reuse as red

    u32* redA = (u32*)smem;             // [128][33]
    u32* redB = (u32*)(smem + 16896);   // [128][9]

    float esA[4], zsB4[4], esB[4][4], zsA[4][4];
    #pragma unroll
    for (int ct = 0; ct < 4; ++ct) {
        esA[ct] = es[col0 + colhalf + ct * 16 + l15];
        #pragma unroll
        for (int reg = 0; reg < 4; ++reg)
            esB[ct][reg] = es[col0 + colhalf + ct * 16 + p * 4 + reg];
    }
    #pragma unroll
    for (int rt = 0; rt < 4; ++rt) {
        zsB4[rt] = zs[row0 + rowhalf + rt * 16 + l15];
        #pragma unroll
        for (int reg = 0; reg < 4; ++reg)
            zsA[rt][reg] = zs[row0 + rowhalf + rt * 16 + p * 4 + reg];
    }

    #pragma unroll
    for (int rt = 0; rt < 4; ++rt) {
        u32 bB = 0xffffffffu;
        #pragma unroll
        for (int reg = 0; reg < 4; ++reg) {
            u32 bA = 0xffffffffu;
            #pragma unroll
            for (int ct = 0; ct < 4; ++ct) {
                float a2 = __fmul_rn(2.0f, acc[rt][ct][reg]);
                float vA = __fsub_rn(__fadd_rn(zsA[rt][reg], esA[ct]), a2);
                float vB = __fsub_rn(__fadd_rn(zsB4[rt], esB[ct][reg]), a2);
                u32 fA = fmap(vA), fB = fmap(vB);
                if (fA < bA) bA = fA;
                if (fB < bB) bB = fB;
            }
            redA[(rowhalf + rt * 16 + p * 4 + reg) * 33 + (w >> 1) * 16 + l15] = bA;
        }
        redB[(rowhalf + rt * 16 + l15) * 9 + (w >> 1) * 4 + p] = bB;
    }
    __syncthreads();
    if (tid < 128) {
        u32 bA = 0xffffffffu, bB = 0xffffffffu;
        #pragma unroll
        for (int s = 0; s < 32; ++s) { u32 v = redA[tid * 33 + s]; if (v < bA) bA = v; }
        #pragma unroll
        for (int s = 0; s < 8; ++s)  { u32 v = redB[tid * 9 + s];  if (v < bB) bB = v; }
        keysA[((size_t)(row0 + tid)) * 64 + bx] = bA;
        keysB[((size_t)(row0 + tid)) * 64 + bx] = bB;
    }

    // fused one-hot zero fill — skip EHL-resident rows (zeroed by k_final)
    if (by < 126) {
        float4 z4 = make_float4(0.f, 0.f, 0.f, 0.f);
        #pragma unroll
        for (int it = 0; it < 16; ++it) {
            int f4 = tid + it * 256;
            int r = f4 >> 5, q = f4 & 31;
            *(float4*)&oh[((size_t)(row0 + r)) * NEMB + col0 + q * 4] = z4;
        }
    }
}

// ---------------------------------------------------------------------------
// exact np-f32 distance key (R3-proven chain; float4 loads, same FMA order)
// ---------------------------------------------------------------------------
__device__ __forceinline__ u64 exact_key4(const float* zrow, const float* __restrict__ E,
                                          const float* __restrict__ es, float zsn, int k) {
    const float4* e4 = (const float4*)&E[(size_t)k * 256];
    float dot = 0.0f;
    #pragma unroll 4
    for (int c4 = 0; c4 < 64; ++c4) {
        float4 ev = e4[c4];
        dot = fmaf(zrow[c4 * 4 + 0], ev.x, dot);
        dot = fmaf(zrow[c4 * 4 + 1], ev.y, dot);
        dot = fmaf(zrow[c4 * 4 + 2], ev.z, dot);
        dot = fmaf(zrow[c4 * 4 + 3], ev.w, dot);
    }
    float t1 = __fadd_rn(zsn, es[k]);
    float d  = __fsub_rn(t1, __fmul_rn(2.0f, dot));
    return ((u64)fmap(d) << 32) | (u32)k;
}

// ---------------------------------------------------------------------------
// Kernel O: decide D-layout orientation once (row 0, 16 chunks, exact vote)
// ---------------------------------------------------------------------------
__global__ __launch_bounds__(256) void k_orient(const float* __restrict__ Z,
                                                const float* __restrict__ E,
                                                const float* __restrict__ es,
                                                const float* __restrict__ zs,
                                                const u32* __restrict__ keysA,
                                                const u32* __restrict__ keysB,
                                                int* __restrict__ orient) {
    __shared__ float zrow[256];
    __shared__ u32 mex[256];
    int tid = threadIdx.x;
    zrow[tid] = Z[tid];   // row 0
    __syncthreads();
    int chunk = tid >> 4, sub = tid & 15;
    float zsn = zs[0];
    u32 best = 0xffffffffu;
    #pragma unroll 2
    for (int j = 0; j < 8; ++j) {
        u64 key = exact_key4(zrow, E, es, zsn, chunk * 128 + sub * 8 + j);
        u32 f = (u32)(key >> 32);
        if (f < best) best = f;
    }
    mex[tid] = best;
    __syncthreads();
    if (tid == 0) {
        int cA = 0, cB = 0;
        for (int s = 0; s < 16; ++s) {
            u32 m = 0xffffffffu;
            for (int t = 0; t < 16; ++t) { u32 v = mex[s * 16 + t]; if (v < m) m = v; }
            if (udiff(keysA[s], m) <= 2u) ++cA;
            if (udiff(keysB[s], m) <= 2u) ++cB;
        }
        *orient = (cA >= 12) ? 0 : (cB >= 12) ? 1 : 2;
    }
}

// ---------------------------------------------------------------------------
// Kernel D: per-row finalize — flag+exact-rescue on the winning keys; per-row
// trip or orient==2 -> full exact scan. Always np-exact.
// ---------------------------------------------------------------------------
__global__ __launch_bounds__(256) void k_final(const float* __restrict__ Z,
                                               const float* __restrict__ E,
                                               const float* __restrict__ es,
                                               const float* __restrict__ zs,
                                               const u32* __restrict__ keysA,
                                               const u32* __restrict__ keysB,
                                               const int* __restrict__ orient,
                                               float* __restrict__ zq,
                                               float* __restrict__ idxf,
                                               float* __restrict__ oh) {
    __shared__ float zrow[256];
    __shared__ u32 kch[64];
    __shared__ u64 rmin[256];
    __shared__ int flaglist[64];
    __shared__ int nflag;
    __shared__ u32 mval;
    __shared__ int strip;

    int n = blockIdx.x, tid = threadIdx.x;
    int ori = *orient;
    const u32* keys = (ori == 1) ? keysB : keysA;

    zrow[tid] = Z[(size_t)n * 256 + tid];
    if (tid < 64) kch[tid] = keys[(size_t)n * 64 + tid];
    __syncthreads();
    if (tid == 0) {
        if (ori == 2) {
            nflag = 64;
            for (int s = 0; s < 64; ++s) flaglist[s] = s;
            mval = 0;
        } else {
            u32 m = 0xffffffffu;
            for (int s = 0; s < 64; ++s) if (kch[s] < m) m = kch[s];
            u32 thr = m + THR_ULP;
            int nf = 0;
            for (int s = 0; s < 64; ++s) if (kch[s] <= thr) flaglist[nf++] = s;
            nflag = nf; mval = m;
        }
    }
    __syncthreads();

    float zsn = zs[n];
    u64 best = ~0ull;
    for (int f = 0; f < nflag; ++f)
        if (tid < 128) {
            u64 key = exact_key4(zrow, E, es, zsn, flaglist[f] * 128 + tid);
            if (key < best) best = key;
        }
    rmin[tid] = best;
    __syncthreads();
    for (int s = 128; s > 0; s >>= 1) {
        if (tid < s) { if (rmin[tid + s] < rmin[tid]) rmin[tid] = rmin[tid + s]; }
        __syncthreads();
    }
    u64 ph1 = rmin[0];
    if (tid == 0)
        strip = (ori != 2) && (udiff((u32)(ph1 >> 32), mval) > TRIP_ULP);
    __syncthreads();

    if (strip) {
        best = ~0ull;
        for (int ch = 0; ch < 64; ++ch)
            if (tid < 128) {
                u64 key = exact_key4(zrow, E, es, zsn, ch * 128 + tid);
                if (key < best) best = key;
            }
        rmin[tid] = best;
        __syncthreads();
        for (int s = 128; s > 0; s >>= 1) {
            if (tid < s) { if (rmin[tid + s] < rmin[tid]) rmin[tid] = rmin[tid + s]; }
            __syncthreads();
        }
    }
    int idx = (int)(rmin[0] & 0xffffffffu);

    // tail rows hosted EHL scratch during k_dist — zero them here
    if (n >= EHL_ROW0) {
        float* ohrow = oh + (size_t)n * NEMB;
        float4 z4 = make_float4(0.f, 0.f, 0.f, 0.f);
        #pragma unroll
        for (int it = 0; it < 8; ++it)
            *(float4*)&ohrow[(it * 256 + tid) * 4] = z4;
        __syncthreads();
    }

    if (tid < 64)
        *(float4*)&zq[(size_t)n * 256 + tid * 4] =
            *(const float4*)&E[(size_t)idx * 256 + tid * 4];
    if (tid == 0) {
        idxf[n] = (float)idx;
        oh[(size_t)n * NEMB + idx] = 1.0f;
    }
}

// ---------------------------------------------------------------------------
extern "C" void kernel_launch(void* const* d_in, const int* in_sizes, int n_in,
                              void* d_out, int out_size, void* d_ws, size_t ws_size,
                              hipStream_t stream) {
    const float* ze  = (const float*)d_in[0];   // [16,256,32,32]
    const float* emb = (const float*)d_in[1];   // [8192,256]
    float* out = (float*)d_out;
    float* z    = out + Z_OFF;
    float* zq   = out + ZQ_OFF;
    float* idxf = out + IDX_OFF;
    float* oh   = out + OH_OFF;
    float* es    = (float*)((char*)d_ws + ES_OFF_BYTES);
    float* zs    = (float*)((char*)d_ws + ZS_OFF_BYTES);
    int*   orient= (int*)((char*)d_ws + ORIENT_OFF_BYTES);
    u32*   keysA = (u32*)((char*)d_ws + KEYSA_OFF_BYTES);
    u32*   keysB = (u32*)((char*)d_ws + KEYSB_OFF_BYTES);
    char*  ZHL  = (char*)zq;                                   // 16 MB (z_q region)
    char*  EHL  = (char*)(oh + (size_t)EHL_ROW0 * NEMB);       // 8 MB (one-hot tail)

    k_transpose<<<dim3(4, 16, 16), 256, 0, stream>>>(ze, z);
    k_zsq<<<NROWS / 256, 256, 0, stream>>>(ze, zs);
    k_rowsq<<<NEMB / 256, 256, 0, stream>>>(emb, es, NEMB);
    k_split<<<NROWS * 32 / 256, 256, 0, stream>>>(z, ZHL, NROWS);
    k_split<<<NEMB * 32 / 256, 256, 0, stream>>>(emb, EHL, NEMB);
    k_dist<<<dim3(64, 128), 256, 0, stream>>>(ZHL, EHL, es, zs, oh, keysA, keysB);
    k_orient<<<1, 256, 0, stream>>>(z, emb, es, zs, keysA, keysB, orient);
    k_final<<<NROWS, 256, 0, stream>>>(z, emb, es, zs, keysA, keysB, orient,
                                       zq, idxf, oh);
}